// Round 3
// baseline (23645.531 us; speedup 1.0000x reference)
//
#include <hip/hip_runtime.h>
#include <math.h>

#define BT 65536      // batch rows
#define NIN 1024      // input dim (reduction)
#define KK 1024       // codes (logit cols)
#define EE 256        // embedding dim
#define MT 64         // rows per block
#define KB 16         // reduction chunk staged per iteration
#define NKC (NIN / KB)
#define WSP 1028      // ws row stride: transpose writes 2-way aliased (free)
#define XSP 16        // xs row stride (natural layout, = KB)
#define XS_SZ (MT * XSP)   // 1024 floats per buffer
#define WS_SZ (KB * WSP)   // 16448 floats per buffer
#define LOGK 6.9314718055994531f

// Fused kernel: logits GEMM + gumbel + softmax stats + argmax + codebook gather
// + avg_p partial accumulation.
//
// Block: 1024 threads = 16 waves, MT=64 rows (halves per-row W staging vs MT=32).
// Wave w: row group g=w>>1 (rows 8g..8g+7), col half h=w&1. Thread tile:
// 8 rows x 8 cols (lg = 64 VGPRs).
// Pipeline: double-buffered LDS; per kc: issue kc+1 global loads -> compute
// kc from buf[cur] -> write regs to buf[cur^1] -> ONE barrier. Global-load
// latency hides under the FMA block.
// B-reads: ds_read_b128 identity-contiguous (conflict-free). A-reads:
// wave-uniform broadcast b64. Per-logit fp32 FMA chain over ascending n is
// identical to the previously passing kernel -> outputs bit-identical.
__global__ __launch_bounds__(1024, 4)
void vq_main(const float* __restrict__ x, const float* __restrict__ gum,
             const float* __restrict__ W, const float* __restrict__ bias,
             const float* __restrict__ cbk, float* __restrict__ out,
             float* __restrict__ gsum) {
    __shared__ __align__(16) float smem[2 * XS_SZ + 2 * WS_SZ];  // 139.8 KB
    const int tid = threadIdx.x;
    const int l   = tid & 63;     // lane
    const int wid = tid >> 6;     // wave 0..15
    const int g   = wid >> 1;     // row group 0..7 -> rows 8g..8g+7
    const int h   = wid & 1;      // col half
    const int row0 = blockIdx.x * MT;

    float lg[8][8];               // [row r][t], col = 512h + 256*(t>>2) + 4l + (t&3)
    #pragma unroll
    for (int r = 0; r < 8; ++r)
        #pragma unroll
        for (int t = 0; t < 8; ++t) lg[r][t] = 0.f;

    const int xr = tid >> 2;          // x stage (threads 0..255): row 0..63
    const int xf = (tid & 3) << 2;    // n-offset 0,4,8,12
    const int cb0 = (h << 9) + (l << 2);

    float4 wreg[4];
    float4 xreg;

    // ---- prologue: load + stage kc=0 into buffer 0 ----
    if (tid < 256) xreg = *(const float4*)(x + (size_t)(row0 + xr) * NIN + xf);
    #pragma unroll
    for (int i = 0; i < 4; ++i) {
        const int flat = tid + (i << 10);
        wreg[i] = *(const float4*)(W + (size_t)(flat >> 2) * NIN + ((flat & 3) << 2));
    }
    {
        float* xsb = smem;
        float* wsb = smem + 2 * XS_SZ;
        if (tid < 256) *(float4*)(xsb + xr * XSP + xf) = xreg;
        #pragma unroll
        for (int i = 0; i < 4; ++i) {
            const int flat = tid + (i << 10);
            const int c  = flat >> 2;
            const int nf = (flat & 3) << 2;
            wsb[(nf + 0) * WSP + c] = wreg[i].x;
            wsb[(nf + 1) * WSP + c] = wreg[i].y;
            wsb[(nf + 2) * WSP + c] = wreg[i].z;
            wsb[(nf + 3) * WSP + c] = wreg[i].w;
        }
    }
    __syncthreads();

    for (int kc = 0; kc < NKC; ++kc) {
        const int cur = kc & 1;
        // issue next-tile global loads; latency hides under the FMAs below
        if (kc + 1 < NKC) {
            const int n1 = (kc + 1) * KB;
            if (tid < 256) xreg = *(const float4*)(x + (size_t)(row0 + xr) * NIN + n1 + xf);
            #pragma unroll
            for (int i = 0; i < 4; ++i) {
                const int flat = tid + (i << 10);
                wreg[i] = *(const float4*)(W + (size_t)(flat >> 2) * NIN + n1 + ((flat & 3) << 2));
            }
        }
        // compute on buffer cur
        const float* xsb = smem + cur * XS_SZ;
        const float* wsb = smem + 2 * XS_SZ + cur * WS_SZ;
        #pragma unroll
        for (int nb = 0; nb < KB / 2; ++nb) {
            float a2[8][2];
            #pragma unroll
            for (int r = 0; r < 8; ++r) {
                const float2 av = *(const float2*)(xsb + ((g << 3) + r) * XSP + (nb << 1));
                a2[r][0] = av.x; a2[r][1] = av.y;
            }
            #pragma unroll
            for (int m = 0; m < 2; ++m) {
                const int n = (nb << 1) + m;
                const float4 b0 = *(const float4*)(wsb + n * WSP + cb0);
                const float4 b1 = *(const float4*)(wsb + n * WSP + cb0 + 256);
                const float bf[8] = {b0.x, b0.y, b0.z, b0.w, b1.x, b1.y, b1.z, b1.w};
                #pragma unroll
                for (int r = 0; r < 8; ++r)
                    #pragma unroll
                    for (int t = 0; t < 8; ++t)
                        lg[r][t] = fmaf(a2[r][m], bf[t], lg[r][t]);
            }
        }
        // stage next tile into the other buffer (its last readers finished at
        // the barrier that ended iteration kc-1)
        if (kc + 1 < NKC) {
            float* xsb2 = smem + (cur ^ 1) * XS_SZ;
            float* wsb2 = smem + 2 * XS_SZ + (cur ^ 1) * WS_SZ;
            if (tid < 256) *(float4*)(xsb2 + xr * XSP + xf) = xreg;
            #pragma unroll
            for (int i = 0; i < 4; ++i) {
                const int flat = tid + (i << 10);
                const int c  = flat >> 2;
                const int nf = (flat & 3) << 2;
                wsb2[(nf + 0) * WSP + c] = wreg[i].x;
                wsb2[(nf + 1) * WSP + c] = wreg[i].y;
                wsb2[(nf + 2) * WSP + c] = wreg[i].z;
                wsb2[(nf + 3) * WSP + c] = wreg[i].w;
            }
        }
        __syncthreads();
    }

    // add bias + gumbel (tau = 1.0); lane-contiguous float4 loads
    {
        const float4 bb0 = *(const float4*)(bias + cb0);
        const float4 bb1 = *(const float4*)(bias + cb0 + 256);
        #pragma unroll
        for (int r = 0; r < 8; ++r) {
            const int row = row0 + (g << 3) + r;
            const float4 g0 = *(const float4*)(gum + (size_t)row * KK + cb0);
            const float4 g1 = *(const float4*)(gum + (size_t)row * KK + cb0 + 256);
            lg[r][0] += bb0.x + g0.x;  lg[r][1] += bb0.y + g0.y;
            lg[r][2] += bb0.z + g0.z;  lg[r][3] += bb0.w + g0.w;
            lg[r][4] += bb1.x + g1.x;  lg[r][5] += bb1.y + g1.y;
            lg[r][6] += bb1.z + g1.z;  lg[r][7] += bb1.w + g1.w;
        }
    }

    // epilogue LDS scratch (staging buffers are dead after the final barrier)
    float* red  = smem;         // [64 rows][2 halves][2: mv, mi-bits] = 256 floats
    float* ssum = smem + 256;   // [64 rows][2 halves] = 128 floats
    float* aggp = smem + 512;   // [1024]

    // Phase A: per-wave (half-row) max/argmax -> LDS
    #pragma unroll
    for (int r = 0; r < 8; ++r) {
        float mv = -1e30f; int mi = 0;
        #pragma unroll
        for (int t = 0; t < 8; ++t) {          // t ascending == col ascending
            const int c = cb0 + ((t >> 2) << 8) + (t & 3);
            if (lg[r][t] > mv) { mv = lg[r][t]; mi = c; }
        }
        #pragma unroll
        for (int off = 1; off < 64; off <<= 1) {
            const float ov = __shfl_xor(mv, off);
            const int   oi = __shfl_xor(mi, off);
            if (ov > mv || (ov == mv && oi < mi)) { mv = ov; mi = oi; }
        }
        if (l == 0) {
            const int idx = (((g << 3) + r) << 2) + (h << 1);
            red[idx]     = mv;
            red[idx + 1] = __int_as_float(mi);
        }
    }
    __syncthreads();

    // Phase B: combine halves, exp + per-half sum -> LDS
    int MI[8];
    #pragma unroll
    for (int r = 0; r < 8; ++r) {
        const int idx = (((g << 3) + r) << 2);
        const float m0 = red[idx],     m1 = red[idx + 2];
        const int   i0 = __float_as_int(red[idx + 1]);
        const int   i1 = __float_as_int(red[idx + 3]);
        float MV; int Mi;
        if (m1 > m0 || (m1 == m0 && i1 < i0)) { MV = m1; Mi = i1; }
        else                                  { MV = m0; Mi = i0; }
        MI[r] = Mi;
        float s = 0.f;
        #pragma unroll
        for (int t = 0; t < 8; ++t) {
            const float e = __expf(lg[r][t] - MV);
            lg[r][t] = e;
            s += e;
        }
        #pragma unroll
        for (int off = 1; off < 64; off <<= 1) s += __shfl_xor(s, off);
        if (l == 0) ssum[(((g << 3) + r) << 1) + h] = s;
    }
    __syncthreads();

    // Phase C: normalize, gather z_q (h==0 wave writes the 256-f row), m
    #pragma unroll
    for (int r = 0; r < 8; ++r) {
        const int sidx = ((g << 3) + r) << 1;
        const float rinv = 1.f / (ssum[sidx] + ssum[sidx + 1]);
        #pragma unroll
        for (int t = 0; t < 8; ++t) lg[r][t] *= rinv;
        const int row = row0 + (g << 3) + r;
        if (h == 0) {
            const float4 cv = *(const float4*)(cbk + (size_t)MI[r] * EE + (l << 2));
            *(float4*)(out + (size_t)row * EE + (l << 2)) = cv;
            if (l == 0) out[(size_t)BT * EE + row] = (float)MI[r];
        }
    }

    // avg_p partials: sum p over this thread's 8 rows, LDS-aggregate per col,
    // then one global atomicAdd per column per block.
    #pragma unroll
    for (int t = 0; t < 8; ++t)
        #pragma unroll
        for (int r = 1; r < 8; ++r) lg[0][t] += lg[r][t];
    for (int q = tid; q < KK; q += 1024) aggp[q] = 0.f;
    __syncthreads();
    #pragma unroll
    for (int t = 0; t < 8; ++t) {
        const int c = cb0 + ((t >> 2) << 8) + (t & 3);
        atomicAdd(&aggp[c], lg[0][t]);   // 8-way contention (one per row group)
    }
    __syncthreads();
    for (int q = tid; q < KK; q += 1024) atomicAdd(&gsum[q], aggp[q]);
}

// Finalize: diversity = sum avg_p * (log(clip(avg_p,1e-9)) + log K); also the
// trailing zero scalar.
__global__ void vq_fin(const float* __restrict__ gsum, float* __restrict__ out) {
    __shared__ float red[4];
    const int tid = threadIdx.x;
    float local = 0.f;
    for (int q = tid; q < KK; q += 256) {
        const float a = gsum[q] * (1.0f / (float)BT);
        local += a * (logf(fmaxf(a, 1e-9f)) + LOGK);
    }
    #pragma unroll
    for (int off = 1; off < 64; off <<= 1) local += __shfl_xor(local, off);
    if ((tid & 63) == 0) red[tid >> 6] = local;
    __syncthreads();
    if (tid == 0) {
        out[(size_t)BT * EE + BT]     = red[0] + red[1] + red[2] + red[3];
        out[(size_t)BT * EE + BT + 1] = 0.f;
    }
}

extern "C" void kernel_launch(void* const* d_in, const int* in_sizes, int n_in,
                              void* d_out, int out_size, void* d_ws, size_t ws_size,
                              hipStream_t stream) {
    const float* x   = (const float*)d_in[0];
    const float* g   = (const float*)d_in[1];
    const float* W   = (const float*)d_in[2];
    const float* b   = (const float*)d_in[3];
    const float* cbk = (const float*)d_in[4];
    float* out  = (float*)d_out;
    float* gsum = (float*)d_ws;

    hipMemsetAsync(gsum, 0, KK * sizeof(float), stream);
    vq_main<<<BT / MT, 1024, 0, stream>>>(x, g, W, b, cbk, out, gsum);
    vq_fin<<<1, 256, 0, stream>>>(gsum, out);
}